// Round 5
// baseline (403.409 us; speedup 1.0000x reference)
//
#include <hip/hip_runtime.h>

#define N_NODES 50000
#define N_EDGES 1600000
#define DIM 64
#define EDIM 32
#define NUM_GRAPHS 128
#define NUM_CLASSES 10
#define NBIN_PAD 50176            // 196*256 >= N_NODES+1
#define NSCAN_BLK 196
#define EPAD_MAX 2200000          // >= sum(ceil(deg/16)*16)
#define NBUCK 196                 // coarse buckets: dst >> 8
#define BCAP 12288                // per-bucket capacity (mean 8163, +45 sigma)
#define ACH 4096                  // edges per binA block
#define NSL 8                     // place_kernel slices per bucket

typedef __attribute__((ext_vector_type(8))) short bf16x8;
typedef __attribute__((ext_vector_type(4))) short short4v;
typedef __attribute__((ext_vector_type(4))) unsigned short ushort4v;
typedef __attribute__((ext_vector_type(4))) float f32x4;

static __device__ __forceinline__ short f2bf(float f) {
    unsigned u = __builtin_bit_cast(unsigned, f);
    u += 0x7fff + ((u >> 16) & 1);   // round-to-nearest-even
    return (short)(u >> 16);
}
static __device__ __forceinline__ float bf2f(short s) {
    unsigned u = ((unsigned)(unsigned short)s) << 16;
    return __builtin_bit_cast(float, u);
}
// pack 2 f32 -> 2 bf16 in one v_cvt_pk_bf16_f32 (no builtin on gfx950)
static __device__ __forceinline__ int cvt_pk_bf16(float lo, float hi) {
    int r;
    asm("v_cvt_pk_bf16_f32 %0, %1, %2" : "=v"(r) : "v"(lo), "v"(hi));
    return r;
}

// ---------------------------------------------------------------------------
// binA: coarse-bucket edges by dst>>8 with LDS staging. No per-edge global
// atomics. record = {edge id, (dst<<16) | src}
// ---------------------------------------------------------------------------
__global__ void __launch_bounds__(256) binA_kernel(
    const int* __restrict__ src, const int* __restrict__ dst,
    int* __restrict__ bcur, int2* __restrict__ bbuf)
{
    __shared__ int hist[256];
    __shared__ int scanb[256];
    __shared__ int bexcl[256];
    __shared__ int cursA[256];
    __shared__ int gbase[256];
    __shared__ int2 st[ACH];

    const int t = threadIdx.x;
    const int e0 = blockIdx.x * ACH;
    const int nv = min(ACH, N_EDGES - e0);

    hist[t] = 0;
    __syncthreads();

    int w1[ACH / 256];
    #pragma unroll
    for (int i = 0; i < ACH / 256; ++i) {
        int idx = t + 256 * i;
        if (idx < nv) {
            int e = e0 + idx;
            int d = dst[e], s = src[e];
            w1[i] = (s & 0xFFFF) | (d << 16);
            atomicAdd(&hist[(unsigned)w1[i] >> 24], 1);
        } else {
            w1[i] = -1;
        }
    }
    __syncthreads();

    // exclusive scan of hist -> bexcl; reserve global runs
    int v = hist[t];
    scanb[t] = v;
    __syncthreads();
    #pragma unroll
    for (int off = 1; off < 256; off <<= 1) {
        int add = (t >= off) ? scanb[t - off] : 0;
        __syncthreads();
        scanb[t] += add;
        __syncthreads();
    }
    int excl = scanb[t] - v;
    bexcl[t] = excl;
    cursA[t] = excl;
    if (v > 0) gbase[t] = atomicAdd(&bcur[t], v);
    __syncthreads();

    // place into LDS staging, sorted by bucket
    #pragma unroll
    for (int i = 0; i < ACH / 256; ++i) {
        int idx = t + 256 * i;
        if (idx < nv) {
            int b = (unsigned)w1[i] >> 24;
            int r = atomicAdd(&cursA[b], 1);
            int2 rec; rec.x = e0 + idx; rec.y = w1[i];
            st[r] = rec;
        }
    }
    __syncthreads();

    // flush: consecutive k within a bucket-run -> consecutive global addrs
    for (int k = t; k < nv; k += 256) {
        int2 rec = st[k];
        int b = (unsigned)rec.y >> 24;
        int pos = gbase[b] + (k - bexcl[b]);
        if (pos < BCAP) bbuf[(size_t)b * BCAP + pos] = rec;
    }
}

// ---------------------------------------------------------------------------
// binB1: per-bucket node histogram in LDS. The atomicAdd RETURN VALUE is a
// unique per-node rank -> recorded in rank16 so final placement needs no
// shared cursor (this is what lets place_kernel use an arbitrary grid).
// ---------------------------------------------------------------------------
__global__ void __launch_bounds__(1024) binB1_kernel(
    const int* __restrict__ bcur, const int2* __restrict__ bbuf,
    int* __restrict__ cnt, unsigned short* __restrict__ rank16)
{
    __shared__ int nodecnt[256];
    const int b = blockIdx.x, t = threadIdx.x;
    if (t < 256) nodecnt[t] = 0;
    __syncthreads();
    const int nb = min(bcur[b], BCAP);
    for (int k = t; k < nb; k += 1024) {
        size_t i = (size_t)b * BCAP + k;
        int2 rec = bbuf[i];
        int dlow = ((unsigned)rec.y >> 16) & 0xFF;
        int r = atomicAdd(&nodecnt[dlow], 1);
        rank16[i] = (unsigned short)r;
    }
    __syncthreads();
    if (t < 256) cnt[b * 256 + t] = nodecnt[t];
}

// Exclusive scan of PADDED degrees (ceil(deg/16)*16) -> pstart.
__global__ void scan_part(const int* __restrict__ cnt, int* __restrict__ pstart,
                          int* __restrict__ partial) {
    __shared__ int sh[256];
    const int b = blockIdx.x, t = threadIdx.x;
    const int i = b * 256 + t;
    int v = ((cnt[i] + 15) >> 4) << 4;
    sh[t] = v;
    __syncthreads();
    #pragma unroll
    for (int off = 1; off < 256; off <<= 1) {
        int add = (t >= off) ? sh[t - off] : 0;
        __syncthreads();
        sh[t] += add;
        __syncthreads();
    }
    pstart[i] = sh[t] - v;
    if (t == 255) partial[b] = sh[t];
}

__global__ void scan_mid(int* __restrict__ partial) {
    __shared__ int sh[256];
    const int t = threadIdx.x;
    int v = (t < NSCAN_BLK) ? partial[t] : 0;
    sh[t] = v;
    __syncthreads();
    #pragma unroll
    for (int off = 1; off < 256; off <<= 1) {
        int add = (t >= off) ? sh[t - off] : 0;
        __syncthreads();
        sh[t] += add;
        __syncthreads();
    }
    if (t < NSCAN_BLK) partial[t] = sh[t] - v;
}

__global__ void scan_add(int* __restrict__ pstart, const int* __restrict__ partial) {
    const int b = blockIdx.x, t = threadIdx.x;
    const int i = b * 256 + t;
    pstart[i] += partial[b];
}

// ---------------------------------------------------------------------------
// place_kernel: deterministic placement p = pstart[node] + rank. High-
// occupancy flat gather: NBUCK*NSL blocks (1568), 2-record unroll -> ~16
// independent loads in flight per thread. Replaces latency-bound binB2
// (196 blocks, serial LDS-cursor chain, 29% occ, 0.7% VALU).
// ---------------------------------------------------------------------------
__global__ void __launch_bounds__(256) place_kernel(
    const int* __restrict__ bcur, const int2* __restrict__ bbuf,
    const unsigned short* __restrict__ rank16,
    const int* __restrict__ pstart, const float* __restrict__ ea,
    unsigned short* __restrict__ ssrc, short* __restrict__ eab)
{
    const int b  = blockIdx.x >> 3;
    const int sl = blockIdx.x & (NSL - 1);
    const int t  = threadIdx.x;
    const int nb = min(bcur[b], BCAP);
    const int chunk = (nb + NSL - 1) / NSL;
    const int k0 = sl * chunk;
    const int k1 = min(k0 + chunk, nb);

    for (int k = k0 + t; k < k1; k += 512) {
        const int kb = k + 256;
        const bool has2 = kb < k1;
        const size_t i1 = (size_t)b * BCAP + k;
        const size_t i2 = has2 ? (size_t)b * BCAP + kb : i1;
        int2 rec1 = bbuf[i1];
        int2 rec2 = bbuf[i2];
        int rk1 = rank16[i1];
        int rk2 = rank16[i2];
        unsigned y1 = (unsigned)rec1.y, y2 = (unsigned)rec2.y;
        int n1 = (b << 8) | ((y1 >> 16) & 0xFF);
        int n2 = (b << 8) | ((y2 >> 16) & 0xFF);
        int p1 = pstart[n1] + rk1;
        int p2 = pstart[n2] + rk2;
        const float* ar1 = ea + (size_t)rec1.x * EDIM;
        const float* ar2 = ea + (size_t)rec2.x * EDIM;
        float4 v1[8], v2[8];
        #pragma unroll
        for (int qq = 0; qq < 4; ++qq) {
            v1[qq]     = *reinterpret_cast<const float4*>(ar1 + 4 * qq);
            v1[qq + 4] = *reinterpret_cast<const float4*>(ar1 + 4 * qq + 16);
            v2[qq]     = *reinterpret_cast<const float4*>(ar2 + 4 * qq);
            v2[qq + 4] = *reinterpret_cast<const float4*>(ar2 + 4 * qq + 16);
        }
        ssrc[p1] = (unsigned short)(y1 & 0xFFFF);
        ssrc[p2] = (unsigned short)(y2 & 0xFFFF);
        int* er1 = (int*)(eab + (size_t)p1 * 32);
        int* er2 = (int*)(eab + (size_t)p2 * 32);
        #pragma unroll
        for (int qq = 0; qq < 4; ++qq) {
            int4 w;
            w.x = cvt_pk_bf16(v1[qq].x, v1[qq].y);
            w.y = cvt_pk_bf16(v1[qq].z, v1[qq].w);
            w.z = cvt_pk_bf16(v1[qq + 4].x, v1[qq + 4].y);
            w.w = cvt_pk_bf16(v1[qq + 4].z, v1[qq + 4].w);
            *reinterpret_cast<int4*>(er1 + 4 * qq) = w;
        }
        #pragma unroll
        for (int qq = 0; qq < 4; ++qq) {
            int4 w;
            w.x = cvt_pk_bf16(v2[qq].x, v2[qq].y);
            w.y = cvt_pk_bf16(v2[qq].z, v2[qq].w);
            w.z = cvt_pk_bf16(v2[qq + 4].x, v2[qq + 4].y);
            w.w = cvt_pk_bf16(v2[qq + 4].z, v2[qq + 4].w);
            *reinterpret_cast<int4*>(er2 + 4 * qq) = w;
        }
    }
}

// ---------------------------------------------------------------------------
// pad_kernel: pad slots (ssrc sentinel + zero eab rows), tnode fill, and
// zero aggr rows for deg-0 nodes. Thread per node.
// ---------------------------------------------------------------------------
__global__ void __launch_bounds__(256) pad_kernel(
    const int* __restrict__ pstart, const int* __restrict__ cnt,
    unsigned short* __restrict__ ssrc, short* __restrict__ eab,
    int* __restrict__ tnode, float* __restrict__ aggr)
{
    int n = blockIdx.x * 256 + threadIdx.x;
    if (n >= N_NODES) return;
    int p0 = pstart[n], deg = cnt[n];
    int pe = p0 + (((deg + 15) >> 4) << 4);
    int4 z; z.x = 0; z.y = 0; z.z = 0; z.w = 0;
    for (int p = p0 + deg; p < pe; ++p) {
        ssrc[p] = (unsigned short)N_NODES;
        int4* er = (int4*)(eab + (size_t)p * 32);
        er[0] = z; er[1] = z; er[2] = z; er[3] = z;
    }
    for (int tt = p0 >> 4; tt < (pe >> 4); ++tt) tnode[tt] = n;
    if (deg == 0) {
        float4 z4; z4.x = 0.f; z4.y = 0.f; z4.z = 0.f; z4.w = 0.f;
        float4* arow = (float4*)(aggr + (size_t)n * 64);
        #pragma unroll
        for (int j = 0; j < 16; ++j) arow[j] = z4;
    }
}

// ---------------------------------------------------------------------------
// xprep: permuted bf16 node features; stored[n][4c+t] = bf16(x[n][16t+c]).
// Row N_NODES (xb and hb) = -1e30 poison.
// ---------------------------------------------------------------------------
__global__ void xprep_kernel(const float* __restrict__ x, short* __restrict__ xb,
                             short* __restrict__ hb) {
    int t = blockIdx.x * blockDim.x + threadIdx.x;
    if (t >= (N_NODES + 1) * 64) return;
    int n = t >> 6, k = t & 63;
    if (n == N_NODES) {
        short pz = f2bf(-1e30f);
        xb[t] = pz;
        hb[t] = pz;
        return;
    }
    int dim = 16 * (k & 3) + (k >> 2);
    xb[(size_t)n * 64 + k] = f2bf(x[(size_t)n * 64 + dim]);
}

// ---------------------------------------------------------------------------
// Edge kernel (streaming): per tile reads 1KB eab sequentially (bf16,
// fragment order), ushort4 ssrc, 4 random 8B xb rows (L2). Wave tile-ranges
// are node-aligned -> exact partition, single writer per node -> flush is a
// plain coalesced store (no atomics, no aggr pre-zero).
// ---------------------------------------------------------------------------
__global__ void __launch_bounds__(256) edge_kernel(
    const short* __restrict__ xb,     // [N+1,64] bf16 permuted (+poison row)
    const short* __restrict__ eab,    // [EPAD,32] bf16 fragment-order rows
    const unsigned short* __restrict__ ssrc, // [EPAD] src (N_NODES pad)
    const float* __restrict__ We,     // [32,64]
    const float* __restrict__ be,     // [64]
    const int*   __restrict__ tnode,  // [ntiles] owning node per tile
    const int*   __restrict__ pstart, // [N+1]; [N]=EPAD
    float* __restrict__ aggr)         // [N,64] (deg-0 rows pre-zeroed by pad)
{
    const int lane = threadIdx.x & 63;
    const int q = lane >> 4;       // 0..3
    const int c = lane & 15;       // 0..15
    const int wave  = (blockIdx.x * blockDim.x + threadIdx.x) >> 6;
    const int nwav  = (gridDim.x * blockDim.x) >> 6;

    const int ntiles = pstart[N_NODES] >> 4;
    int t0 = (int)(((long long)ntiles * wave) / nwav);
    int t1 = (int)(((long long)ntiles * (wave + 1)) / nwav);
    // align both ends forward to node boundaries (deterministic: wave w's t1
    // equals wave w+1's t0)
    while (t0 > 0 && t0 < ntiles && tnode[t0] == tnode[t0 - 1]) ++t0;
    while (t1 > 0 && t1 < ntiles && tnode[t1] == tnode[t1 - 1]) ++t1;
    if (t0 >= t1) return;

    // B fragments for We (32x64 -> 4 col-tiles of 16). k-map matches eab rows.
    bf16x8 bfrag[4];
    #pragma unroll
    for (int t = 0; t < 4; ++t) {
        #pragma unroll
        for (int e = 0; e < 8; ++e) {
            int k = 4 * q + (e & 3) + 16 * (e >> 2);
            bfrag[t][e] = f2bf(We[k * 64 + 16 * t + c]);
        }
    }
    // bias folded into MFMA C operand
    f32x4 cb[4];
    #pragma unroll
    for (int t = 0; t < 4; ++t) {
        float bv = be[16 * t + c];
        cb[t][0] = bv; cb[t][1] = bv; cb[t][2] = bv; cb[t][3] = bv;
    }

    auto clampT = [&](int tt) { return tt < t1 ? tt : t1 - 1; };
    auto loadIdx = [&](int tt, int& tn, ushort4v& s4) {
        tn = tnode[tt];
        s4 = *reinterpret_cast<const ushort4v*>(ssrc + tt * 16 + 4 * q);
    };
    auto loadE = [&](int tt) {
        return *reinterpret_cast<const bf16x8*>(eab + (size_t)tt * 512 + c * 32 + q * 8);
    };

    int prev_n = -1;
    float acc0 = 0.f, acc1 = 0.f, acc2 = 0.f, acc3 = 0.f;

    auto flush = [&](int n) {
        float r0 = acc0 + __shfl_xor(acc0, 16, 64);
        float r1 = acc1 + __shfl_xor(acc1, 16, 64);
        float r2 = acc2 + __shfl_xor(acc2, 16, 64);
        float r3 = acc3 + __shfl_xor(acc3, 16, 64);
        r0 += __shfl_xor(r0, 32, 64);
        r1 += __shfl_xor(r1, 32, 64);
        r2 += __shfl_xor(r2, 32, 64);
        r3 += __shfl_xor(r3, 32, 64);
        float v = (q == 0) ? r0 : (q == 1) ? r1 : (q == 2) ? r2 : r3;
        aggr[(size_t)n * 64 + lane] = v;   // plain store: wave owns this node
    };

    // ---- 2-deep pipeline prologue (idx 2 ahead, eab/xb 1 ahead) ----
    int tnA, tnB;
    ushort4v s4A, s4B;
    loadIdx(t0, tnA, s4A);
    loadIdx(clampT(t0 + 1), tnB, s4B);
    bf16x8 efA = loadE(t0);
    short4v xvA0 = *reinterpret_cast<const short4v*>(xb + (size_t)s4A.x * 64 + 4 * c);
    short4v xvA1 = *reinterpret_cast<const short4v*>(xb + (size_t)s4A.y * 64 + 4 * c);
    short4v xvA2 = *reinterpret_cast<const short4v*>(xb + (size_t)s4A.z * 64 + 4 * c);
    short4v xvA3 = *reinterpret_cast<const short4v*>(xb + (size_t)s4A.w * 64 + 4 * c);

    for (int tile = t0; tile < t1; ++tile) {
        // issue next-tile data
        bf16x8 efB = loadE(clampT(tile + 1));
        short4v yv0 = *reinterpret_cast<const short4v*>(xb + (size_t)s4B.x * 64 + 4 * c);
        short4v yv1 = *reinterpret_cast<const short4v*>(xb + (size_t)s4B.y * 64 + 4 * c);
        short4v yv2 = *reinterpret_cast<const short4v*>(xb + (size_t)s4B.z * 64 + 4 * c);
        short4v yv3 = *reinterpret_cast<const short4v*>(xb + (size_t)s4B.w * 64 + 4 * c);
        int tnC; ushort4v s4C;
        loadIdx(clampT(tile + 2), tnC, s4C);

        // flush when owning node changes (wave-uniform branch)
        if (tnA != prev_n) {
            if (prev_n >= 0) flush(prev_n);
            prev_n = tnA;
            acc0 = acc1 = acc2 = acc3 = 0.f;
        }

        f32x4 d[4];
        #pragma unroll
        for (int t = 0; t < 4; ++t)
            d[t] = __builtin_amdgcn_mfma_f32_16x16x32_bf16(efA, bfrag[t], cb[t], 0, 0, 0);

        // accumulate relu(d + x[src]); pads (-1e30 poison) contribute 0
        const short4v xv[4] = {xvA0, xvA1, xvA2, xvA3};
        #pragma unroll
        for (int r = 0; r < 4; ++r) {
            acc0 += fmaxf(d[0][r] + bf2f(xv[r][0]), 0.f);
            acc1 += fmaxf(d[1][r] + bf2f(xv[r][1]), 0.f);
            acc2 += fmaxf(d[2][r] + bf2f(xv[r][2]), 0.f);
            acc3 += fmaxf(d[3][r] + bf2f(xv[r][3]), 0.f);
        }

        // shift pipeline
        tnA = tnB; s4A = s4B;
        tnB = tnC; s4B = s4C;
        efA = efB;
        xvA0 = yv0; xvA1 = yv1; xvA2 = yv2; xvA3 = yv3;
    }
    if (prev_n >= 0) flush(prev_n);
}

// ---------------------------------------------------------------------------
// Node kernel (MFMA): wave per 16-node tile.
// h = relu((x + aggr) @ Wab + bab); writes f32 h and permuted bf16 hb.
// ---------------------------------------------------------------------------
__global__ void __launch_bounds__(256) node_kernel(
    const float* __restrict__ x,
    const float* __restrict__ aggr,
    const float* __restrict__ Wab,    // [64,64] f32
    const float* __restrict__ bab,    // [64]
    float* __restrict__ out,          // [N,64]
    short* __restrict__ hb)           // [N(+1),64] bf16 permuted
{
    const int lane = threadIdx.x & 63;
    const int q = lane >> 4;
    const int c = lane & 15;
    const int wave = (blockIdx.x * blockDim.x + threadIdx.x) >> 6;
    const int nwav = (gridDim.x * blockDim.x) >> 6;

    bf16x8 bfrag[2][4];
    #pragma unroll
    for (int kk = 0; kk < 2; ++kk) {
        #pragma unroll
        for (int t = 0; t < 4; ++t) {
            #pragma unroll
            for (int e = 0; e < 8; ++e) {
                int k = 32 * kk + 4 * q + (e & 3) + 16 * (e >> 2);
                bfrag[kk][t][e] = f2bf(Wab[k * 64 + 16 * t + c]);
            }
        }
    }
    f32x4 cb[4];
    #pragma unroll
    for (int t = 0; t < 4; ++t) {
        float bv = bab[16 * t + c];
        cb[t][0] = bv; cb[t][1] = bv; cb[t][2] = bv; cb[t][3] = bv;
    }

    const int ntile = N_NODES / 16;   // 3125 exact
    for (int nt = wave; nt < ntile; nt += nwav) {
        const int n0 = nt * 16;
        const float* xr = x    + (size_t)(n0 + c) * 64;
        const float* ar = aggr + (size_t)(n0 + c) * 64;
        float4 v[4];
        #pragma unroll
        for (int j = 0; j < 4; ++j) {
            int off = (j >> 1) * 32 + (j & 1) * 16 + 4 * q;
            float4 a = *reinterpret_cast<const float4*>(xr + off);
            float4 b = *reinterpret_cast<const float4*>(ar + off);
            v[j].x = a.x + b.x; v[j].y = a.y + b.y;
            v[j].z = a.z + b.z; v[j].w = a.w + b.w;
        }
        f32x4 d[4];
        #pragma unroll
        for (int kk = 0; kk < 2; ++kk) {
            int4 ai;
            ai.x = cvt_pk_bf16(v[2 * kk].x, v[2 * kk].y);
            ai.y = cvt_pk_bf16(v[2 * kk].z, v[2 * kk].w);
            ai.z = cvt_pk_bf16(v[2 * kk + 1].x, v[2 * kk + 1].y);
            ai.w = cvt_pk_bf16(v[2 * kk + 1].z, v[2 * kk + 1].w);
            bf16x8 afrag = __builtin_bit_cast(bf16x8, ai);
            #pragma unroll
            for (int t = 0; t < 4; ++t)
                d[t] = __builtin_amdgcn_mfma_f32_16x16x32_bf16(
                    afrag, bfrag[kk][t], kk == 0 ? cb[t] : d[t], 0, 0, 0);
        }
        #pragma unroll
        for (int r = 0; r < 4; ++r) {
            float h0 = fmaxf(d[0][r], 0.f);
            float h1v = fmaxf(d[1][r], 0.f);
            float h2v = fmaxf(d[2][r], 0.f);
            float h3 = fmaxf(d[3][r], 0.f);
            float* orow = out + (size_t)(n0 + 4 * q + r) * 64;
            orow[c]      = h0;
            orow[16 + c] = h1v;
            orow[32 + c] = h2v;
            orow[48 + c] = h3;
            int2 pk;
            pk.x = cvt_pk_bf16(h0, h1v);
            pk.y = cvt_pk_bf16(h2v, h3);
            *reinterpret_cast<int2*>(hb + (size_t)(n0 + 4 * q + r) * 64 + 4 * c) = pk;
        }
    }
}

__global__ void prep_kernel(
    const float* __restrict__ Wa1, const float* __restrict__ ba1,
    const float* __restrict__ Wb1, const float* __restrict__ bb1,
    const float* __restrict__ Wa2, const float* __restrict__ ba2,
    const float* __restrict__ Wb2, const float* __restrict__ bb2,
    float* __restrict__ Wab1, float* __restrict__ bab1,
    float* __restrict__ Wab2, float* __restrict__ bab2)
{
    const int t = threadIdx.x;
    for (int idx = t; idx < 64 * 64; idx += 256) {
        int i = idx >> 6, j = idx & 63;
        float s1 = 0.f, s2 = 0.f;
        for (int m = 0; m < 64; ++m) {
            s1 += Wa1[i * 64 + m] * Wb1[m * 64 + j];
            s2 += Wa2[i * 64 + m] * Wb2[m * 64 + j];
        }
        Wab1[idx] = s1; Wab2[idx] = s2;
    }
    for (int j = t; j < 64; j += 256) {
        float s1 = bb1[j], s2 = bb2[j];
        for (int m = 0; m < 64; ++m) {
            s1 += ba1[m] * Wb1[m * 64 + j];
            s2 += ba2[m] * Wb2[m * 64 + j];
        }
        bab1[j] = s1; bab2[j] = s2;
    }
}

__global__ void __launch_bounds__(256) pool_kernel(
    const float* __restrict__ h,
    const int*   __restrict__ batch,
    float* __restrict__ psum,
    float* __restrict__ pcnt)
{
    const int lane = threadIdx.x & 63;
    const int wave = (blockIdx.x * blockDim.x + threadIdx.x) >> 6;
    const int n0 = wave * 64;
    if (n0 >= N_NODES) return;
    const int nend = min(n0 + 64, N_NODES);

    int cur = batch[n0];
    float acc = 0.f;
    int cnt = 0;
    for (int n = n0; n < nend; ++n) {
        int b = batch[n];
        if (b != cur) {
            atomicAdd(&psum[(size_t)cur * 64 + lane], acc);
            if (lane == 0) atomicAdd(&pcnt[cur], (float)cnt);
            cur = b; acc = 0.f; cnt = 0;
        }
        acc += h[(size_t)n * 64 + lane];
        cnt++;
    }
    atomicAdd(&psum[(size_t)cur * 64 + lane], acc);
    if (lane == 0) atomicAdd(&pcnt[cur], (float)cnt);
}

__global__ void final_kernel(
    const float* __restrict__ psum, const float* __restrict__ pcnt,
    const float* __restrict__ Wf, const float* __restrict__ bfv,
    float* __restrict__ out)
{
    __shared__ float pooled[NUM_GRAPHS * 64];
    __shared__ float logits[NUM_GRAPHS * NUM_CLASSES];
    const int t = threadIdx.x;
    for (int idx = t; idx < NUM_GRAPHS * 64; idx += 256) {
        int g = idx >> 6;
        float cc = pcnt[g];
        cc = cc < 1.f ? 1.f : cc;
        pooled[idx] = psum[idx] / cc;
    }
    __syncthreads();
    for (int idx = t; idx < NUM_GRAPHS * NUM_CLASSES; idx += 256) {
        int g = idx / NUM_CLASSES, cc = idx % NUM_CLASSES;
        float acc = bfv[cc];
        for (int k = 0; k < 64; ++k)
            acc += pooled[g * 64 + k] * Wf[k * NUM_CLASSES + cc];
        logits[idx] = acc;
    }
    __syncthreads();
    if (t < NUM_GRAPHS) {
        float mx = -1e30f;
        for (int cc = 0; cc < NUM_CLASSES; ++cc)
            mx = fmaxf(mx, logits[t * NUM_CLASSES + cc]);
        float s = 0.f;
        float ex[NUM_CLASSES];
        for (int cc = 0; cc < NUM_CLASSES; ++cc) {
            ex[cc] = expf(logits[t * NUM_CLASSES + cc] - mx);
            s += ex[cc];
        }
        for (int cc = 0; cc < NUM_CLASSES; ++cc)
            out[t * NUM_CLASSES + cc] = ex[cc] / s;
    }
}

extern "C" void kernel_launch(void* const* d_in, const int* in_sizes, int n_in,
                              void* d_out, int out_size, void* d_ws, size_t ws_size,
                              hipStream_t stream) {
    const float* x   = (const float*)d_in[0];
    const float* ea  = (const float*)d_in[1];
    const float* We1 = (const float*)d_in[2];
    const float* be1 = (const float*)d_in[3];
    const float* W1a = (const float*)d_in[4];
    const float* b1a = (const float*)d_in[5];
    const float* W1b = (const float*)d_in[6];
    const float* b1b = (const float*)d_in[7];
    const float* We2 = (const float*)d_in[8];
    const float* be2 = (const float*)d_in[9];
    const float* W2a = (const float*)d_in[10];
    const float* b2a = (const float*)d_in[11];
    const float* W2b = (const float*)d_in[12];
    const float* b2b = (const float*)d_in[13];
    const float* Wf  = (const float*)d_in[14];
    const float* bfv = (const float*)d_in[15];
    const int* ei    = (const int*)d_in[16];
    const int* batch = (const int*)d_in[17];
    const int* src = ei;
    const int* dst = ei + N_EDGES;

    // workspace layout (offsets in 4-byte units from base; total ~57.0M ints
    // = 228 MB)
    int* wsb = (int*)d_ws;
    float* aggr = (float*)wsb;                         // [0, 3.2M)
    float* h1   = (float*)(wsb + 3200000);             // [3.2M, 6.4M)
    float* h2   = (float*)(wsb + 6400000);             // [6.4M, 9.6M)
    short* eab  = (short*)(wsb + 9600000);             // 35,200,000 ints
    int2*  bbuf = (int2*)(wsb + 44800000);             // 4,816,896 ints
    short* xb   = (short*)(wsb + 49616896);            // 1,600,032 ints
    short* hb1  = (short*)(wsb + 51216928);            // 1,600,032 ints
    short* hb2  = (short*)(wsb + 52816960);            // 1,600,032 ints
    unsigned short* ssrc = (unsigned short*)(wsb + 54416992); // 1,100,000 ints
    int* tnode  = wsb + 55516992;                      // 137,500 ints
    float* Wab1 = (float*)(wsb + 55654492);            // 4096
    float* bab1 = Wab1 + 4096;                         // 64
    float* Wab2 = bab1 + 64;                           // 4096
    float* bab2 = Wab2 + 4096;                         // 64
    float* psum = bab2 + 64;                           // 8192
    float* pcnt = psum + 8192;                         // 128
    int* cnt    = (int*)(pcnt + 128);                  // NBIN_PAD
    int* pstart = cnt + NBIN_PAD;                      // NBIN_PAD
    int* partial= pstart + NBIN_PAD;                   // 256
    int* bcur   = partial + 256;                       // 256
    unsigned short* rank16 = (unsigned short*)(bcur + 256); // NBUCK*BCAP ushorts

    float* out = (float*)d_out;

    // ---- padded-CSR build: two-pass LDS-staged counting sort with
    //      deterministic ranks (no placement cursor) ----
    hipMemsetAsync(bcur, 0, 256 * sizeof(int), stream);
    binA_kernel<<<(N_EDGES + ACH - 1) / ACH, 256, 0, stream>>>(src, dst, bcur, bbuf);
    binB1_kernel<<<NBUCK, 1024, 0, stream>>>(bcur, bbuf, cnt, rank16);
    scan_part<<<NSCAN_BLK, 256, 0, stream>>>(cnt, pstart, partial);
    scan_mid<<<1, 256, 0, stream>>>(partial);
    scan_add<<<NSCAN_BLK, 256, 0, stream>>>(pstart, partial);
    place_kernel<<<NBUCK * NSL, 256, 0, stream>>>(bcur, bbuf, rank16, pstart, ea,
                                                  ssrc, eab);
    pad_kernel<<<NSCAN_BLK, 256, 0, stream>>>(pstart, cnt, ssrc, eab, tnode, aggr);
    xprep_kernel<<<((N_NODES + 1) * 64 + 255) / 256, 256, 0, stream>>>(x, xb, hb1);

    hipMemsetAsync(psum, 0, (8192 + 128) * sizeof(float), stream);
    prep_kernel<<<1, 256, 0, stream>>>(W1a, b1a, W1b, b1b, W2a, b2a, W2b, b2b,
                                       Wab1, bab1, Wab2, bab2);

    // no aggr memsets: node-aligned wave ownership -> plain stores cover all
    // deg>0 nodes; pad_kernel zeroed deg-0 rows.
    edge_kernel<<<2048, 256, 0, stream>>>(xb, eab, ssrc, We1, be1, tnode, pstart, aggr);
    node_kernel<<<512, 256, 0, stream>>>(x, aggr, Wab1, bab1, h1, hb1);

    edge_kernel<<<2048, 256, 0, stream>>>(hb1, eab, ssrc, We2, be2, tnode, pstart, aggr);
    node_kernel<<<512, 256, 0, stream>>>(h1, aggr, Wab2, bab2, h2, hb2);

    pool_kernel<<<196, 256, 0, stream>>>(h2, batch, psum, pcnt);
    final_kernel<<<1, 256, 0, stream>>>(psum, pcnt, Wf, bfv, out);
}

// Round 6
// 391.167 us; speedup vs baseline: 1.0313x; 1.0313x over previous
//
#include <hip/hip_runtime.h>

#define N_NODES 50000
#define N_EDGES 1600000
#define DIM 64
#define EDIM 32
#define NUM_GRAPHS 128
#define NUM_CLASSES 10
#define NBIN_PAD 50176            // 196*256 >= N_NODES+1
#define NSCAN_BLK 196
#define EPAD_MAX 2200000          // >= sum(ceil(deg/16)*16)
#define NBUCK 196                 // coarse buckets: dst >> 8
#define BCAP 12288                // per-bucket capacity (mean 8163, +45 sigma)
#define ACH 4096                  // edges per binA block

typedef __attribute__((ext_vector_type(8))) short bf16x8;
typedef __attribute__((ext_vector_type(4))) short short4v;
typedef __attribute__((ext_vector_type(4))) unsigned short ushort4v;
typedef __attribute__((ext_vector_type(4))) float f32x4;

static __device__ __forceinline__ short f2bf(float f) {
    unsigned u = __builtin_bit_cast(unsigned, f);
    u += 0x7fff + ((u >> 16) & 1);   // round-to-nearest-even
    return (short)(u >> 16);
}
static __device__ __forceinline__ float bf2f(short s) {
    unsigned u = ((unsigned)(unsigned short)s) << 16;
    return __builtin_bit_cast(float, u);
}
// pack 2 f32 -> 2 bf16 in one v_cvt_pk_bf16_f32 (no builtin on gfx950)
static __device__ __forceinline__ int cvt_pk_bf16(float lo, float hi) {
    int r;
    asm("v_cvt_pk_bf16_f32 %0, %1, %2" : "=v"(r) : "v"(lo), "v"(hi));
    return r;
}

// ---------------------------------------------------------------------------
// binA: coarse-bucket edges by dst>>8 with LDS staging. No per-edge global
// atomics. record = {edge id, (dst<<16) | src}
// ---------------------------------------------------------------------------
__global__ void __launch_bounds__(256) binA_kernel(
    const int* __restrict__ src, const int* __restrict__ dst,
    int* __restrict__ bcur, int2* __restrict__ bbuf)
{
    __shared__ int hist[256];
    __shared__ int scanb[256];
    __shared__ int bexcl[256];
    __shared__ int cursA[256];
    __shared__ int gbase[256];
    __shared__ int2 st[ACH];

    const int t = threadIdx.x;
    const int e0 = blockIdx.x * ACH;
    const int nv = min(ACH, N_EDGES - e0);

    hist[t] = 0;
    __syncthreads();

    int w1[ACH / 256];
    #pragma unroll
    for (int i = 0; i < ACH / 256; ++i) {
        int idx = t + 256 * i;
        if (idx < nv) {
            int e = e0 + idx;
            int d = dst[e], s = src[e];
            w1[i] = (s & 0xFFFF) | (d << 16);
            atomicAdd(&hist[(unsigned)w1[i] >> 24], 1);
        } else {
            w1[i] = -1;
        }
    }
    __syncthreads();

    // exclusive scan of hist -> bexcl; reserve global runs
    int v = hist[t];
    scanb[t] = v;
    __syncthreads();
    #pragma unroll
    for (int off = 1; off < 256; off <<= 1) {
        int add = (t >= off) ? scanb[t - off] : 0;
        __syncthreads();
        scanb[t] += add;
        __syncthreads();
    }
    int excl = scanb[t] - v;
    bexcl[t] = excl;
    cursA[t] = excl;
    if (v > 0) gbase[t] = atomicAdd(&bcur[t], v);
    __syncthreads();

    // place into LDS staging, sorted by bucket
    #pragma unroll
    for (int i = 0; i < ACH / 256; ++i) {
        int idx = t + 256 * i;
        if (idx < nv) {
            int b = (unsigned)w1[i] >> 24;
            int r = atomicAdd(&cursA[b], 1);
            int2 rec; rec.x = e0 + idx; rec.y = w1[i];
            st[r] = rec;
        }
    }
    __syncthreads();

    // flush: consecutive k within a bucket-run -> consecutive global addrs
    for (int k = t; k < nv; k += 256) {
        int2 rec = st[k];
        int b = (unsigned)rec.y >> 24;
        int pos = gbase[b] + (k - bexcl[b]);
        if (pos < BCAP) bbuf[(size_t)b * BCAP + pos] = rec;
    }
}

// ---------------------------------------------------------------------------
// binB1: per-bucket node histogram in LDS. The atomicAdd RETURN VALUE is a
// unique per-node rank -> recorded in rank16 so final placement needs no
// shared cursor.
// ---------------------------------------------------------------------------
__global__ void __launch_bounds__(1024) binB1_kernel(
    const int* __restrict__ bcur, const int2* __restrict__ bbuf,
    int* __restrict__ cnt, unsigned short* __restrict__ rank16)
{
    __shared__ int nodecnt[256];
    const int b = blockIdx.x, t = threadIdx.x;
    if (t < 256) nodecnt[t] = 0;
    __syncthreads();
    const int nb = min(bcur[b], BCAP);
    for (int k = t; k < nb; k += 1024) {
        size_t i = (size_t)b * BCAP + k;
        int2 rec = bbuf[i];
        int dlow = ((unsigned)rec.y >> 16) & 0xFF;
        int r = atomicAdd(&nodecnt[dlow], 1);
        rank16[i] = (unsigned short)r;
    }
    __syncthreads();
    if (t < 256) cnt[b * 256 + t] = nodecnt[t];
}

// Exclusive scan of PADDED degrees (ceil(deg/16)*16) -> pstart.
__global__ void scan_part(const int* __restrict__ cnt, int* __restrict__ pstart,
                          int* __restrict__ partial) {
    __shared__ int sh[256];
    const int b = blockIdx.x, t = threadIdx.x;
    const int i = b * 256 + t;
    int v = ((cnt[i] + 15) >> 4) << 4;
    sh[t] = v;
    __syncthreads();
    #pragma unroll
    for (int off = 1; off < 256; off <<= 1) {
        int add = (t >= off) ? sh[t - off] : 0;
        __syncthreads();
        sh[t] += add;
        __syncthreads();
    }
    pstart[i] = sh[t] - v;
    if (t == 255) partial[b] = sh[t];
}

__global__ void scan_mid(int* __restrict__ partial) {
    __shared__ int sh[256];
    const int t = threadIdx.x;
    int v = (t < NSCAN_BLK) ? partial[t] : 0;
    sh[t] = v;
    __syncthreads();
    #pragma unroll
    for (int off = 1; off < 256; off <<= 1) {
        int add = (t >= off) ? sh[t - off] : 0;
        __syncthreads();
        sh[t] += add;
        __syncthreads();
    }
    if (t < NSCAN_BLK) partial[t] = sh[t] - v;
}

__global__ void scan_add(int* __restrict__ pstart, const int* __restrict__ partial) {
    const int b = blockIdx.x, t = threadIdx.x;
    const int i = b * 256 + t;
    pstart[i] += partial[b];
}

// ---------------------------------------------------------------------------
// pos_kernel: invert the permutation. p = pstart[node] + rank; write
// pos[edge_id] = p (4B scatter into 6.4MB, L2-scale) and ssrc[p] = src
// (16KB bucket-local window). Streaming reads of bbuf/rank16.
// ---------------------------------------------------------------------------
__global__ void __launch_bounds__(1024) pos_kernel(
    const int* __restrict__ bcur, const int2* __restrict__ bbuf,
    const unsigned short* __restrict__ rank16, const int* __restrict__ pstart,
    int* __restrict__ pos, unsigned short* __restrict__ ssrc)
{
    const int b = blockIdx.x, t = threadIdx.x;
    const int nb = min(bcur[b], BCAP);
    for (int k = t; k < nb; k += 1024) {
        size_t i = (size_t)b * BCAP + k;
        int2 rec = bbuf[i];
        unsigned y = (unsigned)rec.y;
        int n = (b << 8) | ((y >> 16) & 0xFF);
        int p = pstart[n] + (int)rank16[i];
        pos[rec.x] = p;
        ssrc[p] = (unsigned short)(y & 0xFFFF);
    }
}

// ---------------------------------------------------------------------------
// eascatter: thread per edge in ORIGINAL order. ea is read fully streamed
// (coalesced 128B/thread); the random side of the permutation is the WRITE
// (full 64B line to eab[pos[e]], fire-and-forget, no RMW, no latency stall).
// Replaces the random-READ gather that capped place_kernel at 1.8 TB/s.
// ---------------------------------------------------------------------------
__global__ void __launch_bounds__(256) eascatter_kernel(
    const float* __restrict__ ea, const int* __restrict__ pos,
    short* __restrict__ eab)
{
    int e = blockIdx.x * 256 + threadIdx.x;
    if (e >= N_EDGES) return;
    int p = pos[e];
    if ((unsigned)p >= (unsigned)EPAD_MAX) return;   // never in practice
    const float* ar = ea + (size_t)e * EDIM;
    int4 w[4];
    #pragma unroll
    for (int qq = 0; qq < 4; ++qq) {
        float4 lo = *reinterpret_cast<const float4*>(ar + 4 * qq);
        float4 hi = *reinterpret_cast<const float4*>(ar + 4 * qq + 16);
        w[qq].x = cvt_pk_bf16(lo.x, lo.y);
        w[qq].y = cvt_pk_bf16(lo.z, lo.w);
        w[qq].z = cvt_pk_bf16(hi.x, hi.y);
        w[qq].w = cvt_pk_bf16(hi.z, hi.w);
    }
    int4* er = (int4*)(eab + (size_t)p * 32);
    er[0] = w[0]; er[1] = w[1]; er[2] = w[2]; er[3] = w[3];
}

// ---------------------------------------------------------------------------
// pad_kernel: pad slots (ssrc sentinel + zero eab rows), tnode fill, and
// zero aggr rows for deg-0 nodes. Thread per node.
// ---------------------------------------------------------------------------
__global__ void __launch_bounds__(256) pad_kernel(
    const int* __restrict__ pstart, const int* __restrict__ cnt,
    unsigned short* __restrict__ ssrc, short* __restrict__ eab,
    int* __restrict__ tnode, float* __restrict__ aggr)
{
    int n = blockIdx.x * 256 + threadIdx.x;
    if (n >= N_NODES) return;
    int p0 = pstart[n], deg = cnt[n];
    int pe = p0 + (((deg + 15) >> 4) << 4);
    int4 z; z.x = 0; z.y = 0; z.z = 0; z.w = 0;
    for (int p = p0 + deg; p < pe; ++p) {
        ssrc[p] = (unsigned short)N_NODES;
        int4* er = (int4*)(eab + (size_t)p * 32);
        er[0] = z; er[1] = z; er[2] = z; er[3] = z;
    }
    for (int tt = p0 >> 4; tt < (pe >> 4); ++tt) tnode[tt] = n;
    if (deg == 0) {
        float4 z4; z4.x = 0.f; z4.y = 0.f; z4.z = 0.f; z4.w = 0.f;
        float4* arow = (float4*)(aggr + (size_t)n * 64);
        #pragma unroll
        for (int j = 0; j < 16; ++j) arow[j] = z4;
    }
}

// ---------------------------------------------------------------------------
// xprep: permuted bf16 node features; stored[n][4c+t] = bf16(x[n][16t+c]).
// Row N_NODES (xb and hb) = -1e30 poison.
// ---------------------------------------------------------------------------
__global__ void xprep_kernel(const float* __restrict__ x, short* __restrict__ xb,
                             short* __restrict__ hb) {
    int t = blockIdx.x * blockDim.x + threadIdx.x;
    if (t >= (N_NODES + 1) * 64) return;
    int n = t >> 6, k = t & 63;
    if (n == N_NODES) {
        short pz = f2bf(-1e30f);
        xb[t] = pz;
        hb[t] = pz;
        return;
    }
    int dim = 16 * (k & 3) + (k >> 2);
    xb[(size_t)n * 64 + k] = f2bf(x[(size_t)n * 64 + dim]);
}

// ---------------------------------------------------------------------------
// Edge kernel (streaming): per tile reads 1KB eab sequentially (bf16,
// fragment order), ushort4 ssrc, 4 random 8B xb rows (L2). Wave tile-ranges
// are node-aligned -> exact partition, single writer per node -> flush is a
// plain coalesced store (no atomics, no aggr pre-zero).
// ---------------------------------------------------------------------------
__global__ void __launch_bounds__(256) edge_kernel(
    const short* __restrict__ xb,     // [N+1,64] bf16 permuted (+poison row)
    const short* __restrict__ eab,    // [EPAD,32] bf16 fragment-order rows
    const unsigned short* __restrict__ ssrc, // [EPAD] src (N_NODES pad)
    const float* __restrict__ We,     // [32,64]
    const float* __restrict__ be,     // [64]
    const int*   __restrict__ tnode,  // [ntiles] owning node per tile
    const int*   __restrict__ pstart, // [N+1]; [N]=EPAD
    float* __restrict__ aggr)         // [N,64] (deg-0 rows pre-zeroed by pad)
{
    const int lane = threadIdx.x & 63;
    const int q = lane >> 4;       // 0..3
    const int c = lane & 15;       // 0..15
    const int wave  = (blockIdx.x * blockDim.x + threadIdx.x) >> 6;
    const int nwav  = (gridDim.x * blockDim.x) >> 6;

    const int ntiles = pstart[N_NODES] >> 4;
    int t0 = (int)(((long long)ntiles * wave) / nwav);
    int t1 = (int)(((long long)ntiles * (wave + 1)) / nwav);
    // align both ends forward to node boundaries (deterministic: wave w's t1
    // equals wave w+1's t0)
    while (t0 > 0 && t0 < ntiles && tnode[t0] == tnode[t0 - 1]) ++t0;
    while (t1 > 0 && t1 < ntiles && tnode[t1] == tnode[t1 - 1]) ++t1;
    if (t0 >= t1) return;

    // B fragments for We (32x64 -> 4 col-tiles of 16). k-map matches eab rows.
    bf16x8 bfrag[4];
    #pragma unroll
    for (int t = 0; t < 4; ++t) {
        #pragma unroll
        for (int e = 0; e < 8; ++e) {
            int k = 4 * q + (e & 3) + 16 * (e >> 2);
            bfrag[t][e] = f2bf(We[k * 64 + 16 * t + c]);
        }
    }
    // bias folded into MFMA C operand
    f32x4 cb[4];
    #pragma unroll
    for (int t = 0; t < 4; ++t) {
        float bv = be[16 * t + c];
        cb[t][0] = bv; cb[t][1] = bv; cb[t][2] = bv; cb[t][3] = bv;
    }

    auto clampT = [&](int tt) { return tt < t1 ? tt : t1 - 1; };
    auto loadIdx = [&](int tt, int& tn, ushort4v& s4) {
        tn = tnode[tt];
        s4 = *reinterpret_cast<const ushort4v*>(ssrc + tt * 16 + 4 * q);
    };
    auto loadE = [&](int tt) {
        return *reinterpret_cast<const bf16x8*>(eab + (size_t)tt * 512 + c * 32 + q * 8);
    };

    int prev_n = -1;
    float acc0 = 0.f, acc1 = 0.f, acc2 = 0.f, acc3 = 0.f;

    auto flush = [&](int n) {
        float r0 = acc0 + __shfl_xor(acc0, 16, 64);
        float r1 = acc1 + __shfl_xor(acc1, 16, 64);
        float r2 = acc2 + __shfl_xor(acc2, 16, 64);
        float r3 = acc3 + __shfl_xor(acc3, 16, 64);
        r0 += __shfl_xor(r0, 32, 64);
        r1 += __shfl_xor(r1, 32, 64);
        r2 += __shfl_xor(r2, 32, 64);
        r3 += __shfl_xor(r3, 32, 64);
        float v = (q == 0) ? r0 : (q == 1) ? r1 : (q == 2) ? r2 : r3;
        aggr[(size_t)n * 64 + lane] = v;   // plain store: wave owns this node
    };

    // ---- 2-deep pipeline prologue (idx 2 ahead, eab/xb 1 ahead) ----
    int tnA, tnB;
    ushort4v s4A, s4B;
    loadIdx(t0, tnA, s4A);
    loadIdx(clampT(t0 + 1), tnB, s4B);
    bf16x8 efA = loadE(t0);
    short4v xvA0 = *reinterpret_cast<const short4v*>(xb + (size_t)s4A.x * 64 + 4 * c);
    short4v xvA1 = *reinterpret_cast<const short4v*>(xb + (size_t)s4A.y * 64 + 4 * c);
    short4v xvA2 = *reinterpret_cast<const short4v*>(xb + (size_t)s4A.z * 64 + 4 * c);
    short4v xvA3 = *reinterpret_cast<const short4v*>(xb + (size_t)s4A.w * 64 + 4 * c);

    for (int tile = t0; tile < t1; ++tile) {
        // issue next-tile data
        bf16x8 efB = loadE(clampT(tile + 1));
        short4v yv0 = *reinterpret_cast<const short4v*>(xb + (size_t)s4B.x * 64 + 4 * c);
        short4v yv1 = *reinterpret_cast<const short4v*>(xb + (size_t)s4B.y * 64 + 4 * c);
        short4v yv2 = *reinterpret_cast<const short4v*>(xb + (size_t)s4B.z * 64 + 4 * c);
        short4v yv3 = *reinterpret_cast<const short4v*>(xb + (size_t)s4B.w * 64 + 4 * c);
        int tnC; ushort4v s4C;
        loadIdx(clampT(tile + 2), tnC, s4C);

        // flush when owning node changes (wave-uniform branch)
        if (tnA != prev_n) {
            if (prev_n >= 0) flush(prev_n);
            prev_n = tnA;
            acc0 = acc1 = acc2 = acc3 = 0.f;
        }

        f32x4 d[4];
        #pragma unroll
        for (int t = 0; t < 4; ++t)
            d[t] = __builtin_amdgcn_mfma_f32_16x16x32_bf16(efA, bfrag[t], cb[t], 0, 0, 0);

        // accumulate relu(d + x[src]); pads (-1e30 poison) contribute 0
        const short4v xv[4] = {xvA0, xvA1, xvA2, xvA3};
        #pragma unroll
        for (int r = 0; r < 4; ++r) {
            acc0 += fmaxf(d[0][r] + bf2f(xv[r][0]), 0.f);
            acc1 += fmaxf(d[1][r] + bf2f(xv[r][1]), 0.f);
            acc2 += fmaxf(d[2][r] + bf2f(xv[r][2]), 0.f);
            acc3 += fmaxf(d[3][r] + bf2f(xv[r][3]), 0.f);
        }

        // shift pipeline
        tnA = tnB; s4A = s4B;
        tnB = tnC; s4B = s4C;
        efA = efB;
        xvA0 = yv0; xvA1 = yv1; xvA2 = yv2; xvA3 = yv3;
    }
    if (prev_n >= 0) flush(prev_n);
}

// ---------------------------------------------------------------------------
// Node kernel (MFMA): wave per 16-node tile.
// h = relu((x + aggr) @ Wab + bab); writes f32 h and permuted bf16 hb.
// ---------------------------------------------------------------------------
__global__ void __launch_bounds__(256) node_kernel(
    const float* __restrict__ x,
    const float* __restrict__ aggr,
    const float* __restrict__ Wab,    // [64,64] f32
    const float* __restrict__ bab,    // [64]
    float* __restrict__ out,          // [N,64]
    short* __restrict__ hb)           // [N(+1),64] bf16 permuted
{
    const int lane = threadIdx.x & 63;
    const int q = lane >> 4;
    const int c = lane & 15;
    const int wave = (blockIdx.x * blockDim.x + threadIdx.x) >> 6;
    const int nwav = (gridDim.x * blockDim.x) >> 6;

    bf16x8 bfrag[2][4];
    #pragma unroll
    for (int kk = 0; kk < 2; ++kk) {
        #pragma unroll
        for (int t = 0; t < 4; ++t) {
            #pragma unroll
            for (int e = 0; e < 8; ++e) {
                int k = 32 * kk + 4 * q + (e & 3) + 16 * (e >> 2);
                bfrag[kk][t][e] = f2bf(Wab[k * 64 + 16 * t + c]);
            }
        }
    }
    f32x4 cb[4];
    #pragma unroll
    for (int t = 0; t < 4; ++t) {
        float bv = bab[16 * t + c];
        cb[t][0] = bv; cb[t][1] = bv; cb[t][2] = bv; cb[t][3] = bv;
    }

    const int ntile = N_NODES / 16;   // 3125 exact
    for (int nt = wave; nt < ntile; nt += nwav) {
        const int n0 = nt * 16;
        const float* xr = x    + (size_t)(n0 + c) * 64;
        const float* ar = aggr + (size_t)(n0 + c) * 64;
        float4 v[4];
        #pragma unroll
        for (int j = 0; j < 4; ++j) {
            int off = (j >> 1) * 32 + (j & 1) * 16 + 4 * q;
            float4 a = *reinterpret_cast<const float4*>(xr + off);
            float4 b = *reinterpret_cast<const float4*>(ar + off);
            v[j].x = a.x + b.x; v[j].y = a.y + b.y;
            v[j].z = a.z + b.z; v[j].w = a.w + b.w;
        }
        f32x4 d[4];
        #pragma unroll
        for (int kk = 0; kk < 2; ++kk) {
            int4 ai;
            ai.x = cvt_pk_bf16(v[2 * kk].x, v[2 * kk].y);
            ai.y = cvt_pk_bf16(v[2 * kk].z, v[2 * kk].w);
            ai.z = cvt_pk_bf16(v[2 * kk + 1].x, v[2 * kk + 1].y);
            ai.w = cvt_pk_bf16(v[2 * kk + 1].z, v[2 * kk + 1].w);
            bf16x8 afrag = __builtin_bit_cast(bf16x8, ai);
            #pragma unroll
            for (int t = 0; t < 4; ++t)
                d[t] = __builtin_amdgcn_mfma_f32_16x16x32_bf16(
                    afrag, bfrag[kk][t], kk == 0 ? cb[t] : d[t], 0, 0, 0);
        }
        #pragma unroll
        for (int r = 0; r < 4; ++r) {
            float h0 = fmaxf(d[0][r], 0.f);
            float h1v = fmaxf(d[1][r], 0.f);
            float h2v = fmaxf(d[2][r], 0.f);
            float h3 = fmaxf(d[3][r], 0.f);
            float* orow = out + (size_t)(n0 + 4 * q + r) * 64;
            orow[c]      = h0;
            orow[16 + c] = h1v;
            orow[32 + c] = h2v;
            orow[48 + c] = h3;
            int2 pk;
            pk.x = cvt_pk_bf16(h0, h1v);
            pk.y = cvt_pk_bf16(h2v, h3);
            *reinterpret_cast<int2*>(hb + (size_t)(n0 + 4 * q + r) * 64 + 4 * c) = pk;
        }
    }
}

__global__ void prep_kernel(
    const float* __restrict__ Wa1, const float* __restrict__ ba1,
    const float* __restrict__ Wb1, const float* __restrict__ bb1,
    const float* __restrict__ Wa2, const float* __restrict__ ba2,
    const float* __restrict__ Wb2, const float* __restrict__ bb2,
    float* __restrict__ Wab1, float* __restrict__ bab1,
    float* __restrict__ Wab2, float* __restrict__ bab2)
{
    const int t = threadIdx.x;
    for (int idx = t; idx < 64 * 64; idx += 256) {
        int i = idx >> 6, j = idx & 63;
        float s1 = 0.f, s2 = 0.f;
        for (int m = 0; m < 64; ++m) {
            s1 += Wa1[i * 64 + m] * Wb1[m * 64 + j];
            s2 += Wa2[i * 64 + m] * Wb2[m * 64 + j];
        }
        Wab1[idx] = s1; Wab2[idx] = s2;
    }
    for (int j = t; j < 64; j += 256) {
        float s1 = bb1[j], s2 = bb2[j];
        for (int m = 0; m < 64; ++m) {
            s1 += ba1[m] * Wb1[m * 64 + j];
            s2 += ba2[m] * Wb2[m * 64 + j];
        }
        bab1[j] = s1; bab2[j] = s2;
    }
}

__global__ void __launch_bounds__(256) pool_kernel(
    const float* __restrict__ h,
    const int*   __restrict__ batch,
    float* __restrict__ psum,
    float* __restrict__ pcnt)
{
    const int lane = threadIdx.x & 63;
    const int wave = (blockIdx.x * blockDim.x + threadIdx.x) >> 6;
    const int n0 = wave * 64;
    if (n0 >= N_NODES) return;
    const int nend = min(n0 + 64, N_NODES);

    int cur = batch[n0];
    float acc = 0.f;
    int cnt = 0;
    for (int n = n0; n < nend; ++n) {
        int b = batch[n];
        if (b != cur) {
            atomicAdd(&psum[(size_t)cur * 64 + lane], acc);
            if (lane == 0) atomicAdd(&pcnt[cur], (float)cnt);
            cur = b; acc = 0.f; cnt = 0;
        }
        acc += h[(size_t)n * 64 + lane];
        cnt++;
    }
    atomicAdd(&psum[(size_t)cur * 64 + lane], acc);
    if (lane == 0) atomicAdd(&pcnt[cur], (float)cnt);
}

__global__ void final_kernel(
    const float* __restrict__ psum, const float* __restrict__ pcnt,
    const float* __restrict__ Wf, const float* __restrict__ bfv,
    float* __restrict__ out)
{
    __shared__ float pooled[NUM_GRAPHS * 64];
    __shared__ float logits[NUM_GRAPHS * NUM_CLASSES];
    const int t = threadIdx.x;
    for (int idx = t; idx < NUM_GRAPHS * 64; idx += 256) {
        int g = idx >> 6;
        float cc = pcnt[g];
        cc = cc < 1.f ? 1.f : cc;
        pooled[idx] = psum[idx] / cc;
    }
    __syncthreads();
    for (int idx = t; idx < NUM_GRAPHS * NUM_CLASSES; idx += 256) {
        int g = idx / NUM_CLASSES, cc = idx % NUM_CLASSES;
        float acc = bfv[cc];
        for (int k = 0; k < 64; ++k)
            acc += pooled[g * 64 + k] * Wf[k * NUM_CLASSES + cc];
        logits[idx] = acc;
    }
    __syncthreads();
    if (t < NUM_GRAPHS) {
        float mx = -1e30f;
        for (int cc = 0; cc < NUM_CLASSES; ++cc)
            mx = fmaxf(mx, logits[t * NUM_CLASSES + cc]);
        float s = 0.f;
        float ex[NUM_CLASSES];
        for (int cc = 0; cc < NUM_CLASSES; ++cc) {
            ex[cc] = expf(logits[t * NUM_CLASSES + cc] - mx);
            s += ex[cc];
        }
        for (int cc = 0; cc < NUM_CLASSES; ++cc)
            out[t * NUM_CLASSES + cc] = ex[cc] / s;
    }
}

extern "C" void kernel_launch(void* const* d_in, const int* in_sizes, int n_in,
                              void* d_out, int out_size, void* d_ws, size_t ws_size,
                              hipStream_t stream) {
    const float* x   = (const float*)d_in[0];
    const float* ea  = (const float*)d_in[1];
    const float* We1 = (const float*)d_in[2];
    const float* be1 = (const float*)d_in[3];
    const float* W1a = (const float*)d_in[4];
    const float* b1a = (const float*)d_in[5];
    const float* W1b = (const float*)d_in[6];
    const float* b1b = (const float*)d_in[7];
    const float* We2 = (const float*)d_in[8];
    const float* be2 = (const float*)d_in[9];
    const float* W2a = (const float*)d_in[10];
    const float* b2a = (const float*)d_in[11];
    const float* W2b = (const float*)d_in[12];
    const float* b2b = (const float*)d_in[13];
    const float* Wf  = (const float*)d_in[14];
    const float* bfv = (const float*)d_in[15];
    const int* ei    = (const int*)d_in[16];
    const int* batch = (const int*)d_in[17];
    const int* src = ei;
    const int* dst = ei + N_EDGES;

    // workspace layout (offsets in 4-byte units from base; total ~58.6M ints
    // = 234 MB)
    int* wsb = (int*)d_ws;
    float* aggr = (float*)wsb;                         // [0, 3.2M)
    float* h1   = (float*)(wsb + 3200000);             // [3.2M, 6.4M)
    float* h2   = (float*)(wsb + 6400000);             // [6.4M, 9.6M)
    short* eab  = (short*)(wsb + 9600000);             // 35,200,000 ints
    int2*  bbuf = (int2*)(wsb + 44800000);             // 4,816,896 ints
    short* xb   = (short*)(wsb + 49616896);            // 1,600,032 ints
    short* hb1  = (short*)(wsb + 51216928);            // 1,600,032 ints
    short* hb2  = (short*)(wsb + 52816960);            // 1,600,032 ints
    unsigned short* ssrc = (unsigned short*)(wsb + 54416992); // 1,100,000 ints
    int* tnode  = wsb + 55516992;                      // 137,500 ints
    float* Wab1 = (float*)(wsb + 55654492);            // 4096
    float* bab1 = Wab1 + 4096;                         // 64
    float* Wab2 = bab1 + 64;                           // 4096
    float* bab2 = Wab2 + 4096;                         // 64
    float* psum = bab2 + 64;                           // 8192
    float* pcnt = psum + 8192;                         // 128
    int* cnt    = (int*)(pcnt + 128);                  // NBIN_PAD
    int* pstart = cnt + NBIN_PAD;                      // NBIN_PAD
    int* partial= pstart + NBIN_PAD;                   // 256
    int* bcur   = partial + 256;                       // 256
    unsigned short* rank16 = (unsigned short*)(bcur + 256); // NBUCK*BCAP ushorts
    int* pos    = (int*)(rank16 + (size_t)NBUCK * BCAP);    // N_EDGES ints

    float* out = (float*)d_out;

    // ---- padded-CSR build: counting sort with deterministic ranks; the
    //      permutation is applied as a streaming-read + line-granular
    //      random-WRITE scatter (eascatter) ----
    hipMemsetAsync(bcur, 0, 256 * sizeof(int), stream);
    binA_kernel<<<(N_EDGES + ACH - 1) / ACH, 256, 0, stream>>>(src, dst, bcur, bbuf);
    binB1_kernel<<<NBUCK, 1024, 0, stream>>>(bcur, bbuf, cnt, rank16);
    scan_part<<<NSCAN_BLK, 256, 0, stream>>>(cnt, pstart, partial);
    scan_mid<<<1, 256, 0, stream>>>(partial);
    scan_add<<<NSCAN_BLK, 256, 0, stream>>>(pstart, partial);
    pos_kernel<<<NBUCK, 1024, 0, stream>>>(bcur, bbuf, rank16, pstart, pos, ssrc);
    eascatter_kernel<<<(N_EDGES + 255) / 256, 256, 0, stream>>>(ea, pos, eab);
    pad_kernel<<<NSCAN_BLK, 256, 0, stream>>>(pstart, cnt, ssrc, eab, tnode, aggr);
    xprep_kernel<<<((N_NODES + 1) * 64 + 255) / 256, 256, 0, stream>>>(x, xb, hb1);

    hipMemsetAsync(psum, 0, (8192 + 128) * sizeof(float), stream);
    prep_kernel<<<1, 256, 0, stream>>>(W1a, b1a, W1b, b1b, W2a, b2a, W2b, b2b,
                                       Wab1, bab1, Wab2, bab2);

    // no aggr memsets: node-aligned wave ownership -> plain stores cover all
    // deg>0 nodes; pad_kernel zeroed deg-0 rows.
    edge_kernel<<<2048, 256, 0, stream>>>(xb, eab, ssrc, We1, be1, tnode, pstart, aggr);
    node_kernel<<<512, 256, 0, stream>>>(x, aggr, Wab1, bab1, h1, hb1);

    edge_kernel<<<2048, 256, 0, stream>>>(hb1, eab, ssrc, We2, be2, tnode, pstart, aggr);
    node_kernel<<<512, 256, 0, stream>>>(h1, aggr, Wab2, bab2, h2, hb2);

    pool_kernel<<<196, 256, 0, stream>>>(h2, batch, psum, pcnt);
    final_kernel<<<1, 256, 0, stream>>>(psum, pcnt, Wf, bfv, out);
}

// Round 7
// 368.773 us; speedup vs baseline: 1.0939x; 1.0607x over previous
//
#include <hip/hip_runtime.h>

#define N_NODES 50000
#define N_EDGES 1600000
#define DIM 64
#define EDIM 32
#define NUM_GRAPHS 128
#define NUM_CLASSES 10
#define NBIN_PAD 50176            // 196*256 >= N_NODES+1
#define NSCAN_BLK 196
#define EPAD_MAX 2200000          // >= sum(ceil(deg/16)*16)
#define NBUCK 196                 // coarse buckets: dst >> 8
#define BCAP 12288                // per-bucket capacity (mean 8163, +45 sigma)
#define ACH 4096                  // edges per binA block

typedef __attribute__((ext_vector_type(8))) short bf16x8;
typedef __attribute__((ext_vector_type(4))) short short4v;
typedef __attribute__((ext_vector_type(4))) unsigned short ushort4v;
typedef __attribute__((ext_vector_type(4))) float f32x4;

static __device__ __forceinline__ short f2bf(float f) {
    unsigned u = __builtin_bit_cast(unsigned, f);
    u += 0x7fff + ((u >> 16) & 1);   // round-to-nearest-even
    return (short)(u >> 16);
}
static __device__ __forceinline__ float bf2f(short s) {
    unsigned u = ((unsigned)(unsigned short)s) << 16;
    return __builtin_bit_cast(float, u);
}
// pack 2 f32 -> 2 bf16 in one v_cvt_pk_bf16_f32 (no builtin on gfx950)
static __device__ __forceinline__ int cvt_pk_bf16(float lo, float hi) {
    int r;
    asm("v_cvt_pk_bf16_f32 %0, %1, %2" : "=v"(r) : "v"(lo), "v"(hi));
    return r;
}

// ---------------------------------------------------------------------------
// binA: coarse-bucket edges by dst>>8 with LDS staging. No per-edge global
// atomics. record = {edge id, (dst<<16) | src}
// ---------------------------------------------------------------------------
__global__ void __launch_bounds__(256) binA_kernel(
    const int* __restrict__ src, const int* __restrict__ dst,
    int* __restrict__ bcur, int2* __restrict__ bbuf)
{
    __shared__ int hist[256];
    __shared__ int scanb[256];
    __shared__ int bexcl[256];
    __shared__ int cursA[256];
    __shared__ int gbase[256];
    __shared__ int2 st[ACH];

    const int t = threadIdx.x;
    const int e0 = blockIdx.x * ACH;
    const int nv = min(ACH, N_EDGES - e0);

    hist[t] = 0;
    __syncthreads();

    int w1[ACH / 256];
    #pragma unroll
    for (int i = 0; i < ACH / 256; ++i) {
        int idx = t + 256 * i;
        if (idx < nv) {
            int e = e0 + idx;
            int d = dst[e], s = src[e];
            w1[i] = (s & 0xFFFF) | (d << 16);
            atomicAdd(&hist[(unsigned)w1[i] >> 24], 1);
        } else {
            w1[i] = -1;
        }
    }
    __syncthreads();

    // exclusive scan of hist -> bexcl; reserve global runs
    int v = hist[t];
    scanb[t] = v;
    __syncthreads();
    #pragma unroll
    for (int off = 1; off < 256; off <<= 1) {
        int add = (t >= off) ? scanb[t - off] : 0;
        __syncthreads();
        scanb[t] += add;
        __syncthreads();
    }
    int excl = scanb[t] - v;
    bexcl[t] = excl;
    cursA[t] = excl;
    if (v > 0) gbase[t] = atomicAdd(&bcur[t], v);
    __syncthreads();

    // place into LDS staging, sorted by bucket
    #pragma unroll
    for (int i = 0; i < ACH / 256; ++i) {
        int idx = t + 256 * i;
        if (idx < nv) {
            int b = (unsigned)w1[i] >> 24;
            int r = atomicAdd(&cursA[b], 1);
            int2 rec; rec.x = e0 + idx; rec.y = w1[i];
            st[r] = rec;
        }
    }
    __syncthreads();

    // flush: consecutive k within a bucket-run -> consecutive global addrs
    for (int k = t; k < nv; k += 256) {
        int2 rec = st[k];
        int b = (unsigned)rec.y >> 24;
        int pos = gbase[b] + (k - bexcl[b]);
        if (pos < BCAP) bbuf[(size_t)b * BCAP + pos] = rec;
    }
}

// ---------------------------------------------------------------------------
// binB1: per-bucket node histogram in LDS. The atomicAdd RETURN VALUE is a
// unique per-node rank -> recorded in rank16 so final placement needs no
// shared cursor.
// ---------------------------------------------------------------------------
__global__ void __launch_bounds__(1024) binB1_kernel(
    const int* __restrict__ bcur, const int2* __restrict__ bbuf,
    int* __restrict__ cnt, unsigned short* __restrict__ rank16)
{
    __shared__ int nodecnt[256];
    const int b = blockIdx.x, t = threadIdx.x;
    if (t < 256) nodecnt[t] = 0;
    __syncthreads();
    const int nb = min(bcur[b], BCAP);
    for (int k = t; k < nb; k += 1024) {
        size_t i = (size_t)b * BCAP + k;
        int2 rec = bbuf[i];
        int dlow = ((unsigned)rec.y >> 16) & 0xFF;
        int r = atomicAdd(&nodecnt[dlow], 1);
        rank16[i] = (unsigned short)r;
    }
    __syncthreads();
    if (t < 256) cnt[b * 256 + t] = nodecnt[t];
}

// Exclusive scan of PADDED degrees (ceil(deg/16)*16) -> pstart.
__global__ void scan_part(const int* __restrict__ cnt, int* __restrict__ pstart,
                          int* __restrict__ partial) {
    __shared__ int sh[256];
    const int b = blockIdx.x, t = threadIdx.x;
    const int i = b * 256 + t;
    int v = ((cnt[i] + 15) >> 4) << 4;
    sh[t] = v;
    __syncthreads();
    #pragma unroll
    for (int off = 1; off < 256; off <<= 1) {
        int add = (t >= off) ? sh[t - off] : 0;
        __syncthreads();
        sh[t] += add;
        __syncthreads();
    }
    pstart[i] = sh[t] - v;
    if (t == 255) partial[b] = sh[t];
}

__global__ void scan_mid(int* __restrict__ partial) {
    __shared__ int sh[256];
    const int t = threadIdx.x;
    int v = (t < NSCAN_BLK) ? partial[t] : 0;
    sh[t] = v;
    __syncthreads();
    #pragma unroll
    for (int off = 1; off < 256; off <<= 1) {
        int add = (t >= off) ? sh[t - off] : 0;
        __syncthreads();
        sh[t] += add;
        __syncthreads();
    }
    if (t < NSCAN_BLK) partial[t] = sh[t] - v;
}

__global__ void scan_add(int* __restrict__ pstart, const int* __restrict__ partial) {
    const int b = blockIdx.x, t = threadIdx.x;
    const int i = b * 256 + t;
    pstart[i] += partial[b];
}

// ---------------------------------------------------------------------------
// pos_kernel: invert the permutation. p = pstart[node] + rank; write
// pos[edge_id] = p (4B scatter into 6.4MB, L2-scale) and ssrc[p] = src
// (bucket-local window). Streaming reads of bbuf/rank16.
// ---------------------------------------------------------------------------
__global__ void __launch_bounds__(1024) pos_kernel(
    const int* __restrict__ bcur, const int2* __restrict__ bbuf,
    const unsigned short* __restrict__ rank16, const int* __restrict__ pstart,
    int* __restrict__ pos, unsigned short* __restrict__ ssrc)
{
    const int b = blockIdx.x, t = threadIdx.x;
    const int nb = min(bcur[b], BCAP);
    for (int k = t; k < nb; k += 1024) {
        size_t i = (size_t)b * BCAP + k;
        int2 rec = bbuf[i];
        unsigned y = (unsigned)rec.y;
        int n = (b << 8) | ((y >> 16) & 0xFF);
        int p = pstart[n] + (int)rank16[i];
        pos[rec.x] = p;
        ssrc[p] = (unsigned short)(y & 0xFFFF);
    }
}

// ---------------------------------------------------------------------------
// eascatter v2: 4 LANES PER EDGE. Sublane s (lane&3) handles 16B of edge
// i (lane>>2): reads float4 @ row*32+4s and +16 (wave load = 16 contiguous
// 64B half-rows, coalesced), writes int4 @ eab[p]*32+8s. One wave-wide
// store instruction covers 16 FULL 64B lines (4 consecutive lanes per line)
// -> 1.6M full-line write transactions instead of 6.4M 16B partials.
// Tests whether round-6's 1.8 TB/s was transaction-rate- or DRAM-bound.
// ---------------------------------------------------------------------------
__global__ void __launch_bounds__(256) eascatter_kernel(
    const float* __restrict__ ea, const int* __restrict__ pos,
    short* __restrict__ eab)
{
    const int gid  = blockIdx.x * 256 + threadIdx.x;
    const int wv   = gid >> 6;
    const int lane = threadIdx.x & 63;
    const int i = lane >> 2;       // edge within wave group
    const int s = lane & 3;        // 16B sublane within row
    const int e = wv * 16 + i;
    if (e >= N_EDGES) return;
    int p = pos[e];
    if ((unsigned)p >= (unsigned)EPAD_MAX) return;   // never in practice
    const float* ar = ea + (size_t)e * EDIM + 4 * s;
    float4 lo = *reinterpret_cast<const float4*>(ar);        // f[4s..4s+4)
    float4 hi = *reinterpret_cast<const float4*>(ar + 16);   // f[4s+16..+4)
    int4 w;
    w.x = cvt_pk_bf16(lo.x, lo.y);
    w.y = cvt_pk_bf16(lo.z, lo.w);
    w.z = cvt_pk_bf16(hi.x, hi.y);
    w.w = cvt_pk_bf16(hi.z, hi.w);
    *reinterpret_cast<int4*>(eab + (size_t)p * 32 + 8 * s) = w;
}

// ---------------------------------------------------------------------------
// pad_kernel: pad slots (ssrc sentinel + zero eab rows), tnode fill, and
// zero aggr rows for deg-0 nodes. Thread per node.
// ---------------------------------------------------------------------------
__global__ void __launch_bounds__(256) pad_kernel(
    const int* __restrict__ pstart, const int* __restrict__ cnt,
    unsigned short* __restrict__ ssrc, short* __restrict__ eab,
    int* __restrict__ tnode, float* __restrict__ aggr)
{
    int n = blockIdx.x * 256 + threadIdx.x;
    if (n >= N_NODES) return;
    int p0 = pstart[n], deg = cnt[n];
    int pe = p0 + (((deg + 15) >> 4) << 4);
    int4 z; z.x = 0; z.y = 0; z.z = 0; z.w = 0;
    for (int p = p0 + deg; p < pe; ++p) {
        ssrc[p] = (unsigned short)N_NODES;
        int4* er = (int4*)(eab + (size_t)p * 32);
        er[0] = z; er[1] = z; er[2] = z; er[3] = z;
    }
    for (int tt = p0 >> 4; tt < (pe >> 4); ++tt) tnode[tt] = n;
    if (deg == 0) {
        float4 z4; z4.x = 0.f; z4.y = 0.f; z4.z = 0.f; z4.w = 0.f;
        float4* arow = (float4*)(aggr + (size_t)n * 64);
        #pragma unroll
        for (int j = 0; j < 16; ++j) arow[j] = z4;
    }
}

// ---------------------------------------------------------------------------
// xprep: permuted bf16 node features; stored[n][4c+t] = bf16(x[n][16t+c]).
// Row N_NODES (xb and hb) = -1e30 poison.
// ---------------------------------------------------------------------------
__global__ void xprep_kernel(const float* __restrict__ x, short* __restrict__ xb,
                             short* __restrict__ hb) {
    int t = blockIdx.x * blockDim.x + threadIdx.x;
    if (t >= (N_NODES + 1) * 64) return;
    int n = t >> 6, k = t & 63;
    if (n == N_NODES) {
        short pz = f2bf(-1e30f);
        xb[t] = pz;
        hb[t] = pz;
        return;
    }
    int dim = 16 * (k & 3) + (k >> 2);
    xb[(size_t)n * 64 + k] = f2bf(x[(size_t)n * 64 + dim]);
}

// ---------------------------------------------------------------------------
// Edge kernel (streaming): per tile reads 1KB eab sequentially (bf16,
// fragment order), ushort4 ssrc, 4 random 8B xb rows (L2). Wave tile-ranges
// are node-aligned -> exact partition, single writer per node -> flush is a
// plain coalesced store (no atomics, no aggr pre-zero).
// ---------------------------------------------------------------------------
__global__ void __launch_bounds__(256) edge_kernel(
    const short* __restrict__ xb,     // [N+1,64] bf16 permuted (+poison row)
    const short* __restrict__ eab,    // [EPAD,32] bf16 fragment-order rows
    const unsigned short* __restrict__ ssrc, // [EPAD] src (N_NODES pad)
    const float* __restrict__ We,     // [32,64]
    const float* __restrict__ be,     // [64]
    const int*   __restrict__ tnode,  // [ntiles] owning node per tile
    const int*   __restrict__ pstart, // [N+1]; [N]=EPAD
    float* __restrict__ aggr)         // [N,64] (deg-0 rows pre-zeroed by pad)
{
    const int lane = threadIdx.x & 63;
    const int q = lane >> 4;       // 0..3
    const int c = lane & 15;       // 0..15
    const int wave  = (blockIdx.x * blockDim.x + threadIdx.x) >> 6;
    const int nwav  = (gridDim.x * blockDim.x) >> 6;

    const int ntiles = pstart[N_NODES] >> 4;
    int t0 = (int)(((long long)ntiles * wave) / nwav);
    int t1 = (int)(((long long)ntiles * (wave + 1)) / nwav);
    // align both ends forward to node boundaries (deterministic: wave w's t1
    // equals wave w+1's t0)
    while (t0 > 0 && t0 < ntiles && tnode[t0] == tnode[t0 - 1]) ++t0;
    while (t1 > 0 && t1 < ntiles && tnode[t1] == tnode[t1 - 1]) ++t1;
    if (t0 >= t1) return;

    // B fragments for We (32x64 -> 4 col-tiles of 16). k-map matches eab rows.
    bf16x8 bfrag[4];
    #pragma unroll
    for (int t = 0; t < 4; ++t) {
        #pragma unroll
        for (int e = 0; e < 8; ++e) {
            int k = 4 * q + (e & 3) + 16 * (e >> 2);
            bfrag[t][e] = f2bf(We[k * 64 + 16 * t + c]);
        }
    }
    // bias folded into MFMA C operand
    f32x4 cb[4];
    #pragma unroll
    for (int t = 0; t < 4; ++t) {
        float bv = be[16 * t + c];
        cb[t][0] = bv; cb[t][1] = bv; cb[t][2] = bv; cb[t][3] = bv;
    }

    auto clampT = [&](int tt) { return tt < t1 ? tt : t1 - 1; };
    auto loadIdx = [&](int tt, int& tn, ushort4v& s4) {
        tn = tnode[tt];
        s4 = *reinterpret_cast<const ushort4v*>(ssrc + tt * 16 + 4 * q);
    };
    auto loadE = [&](int tt) {
        return *reinterpret_cast<const bf16x8*>(eab + (size_t)tt * 512 + c * 32 + q * 8);
    };

    int prev_n = -1;
    float acc0 = 0.f, acc1 = 0.f, acc2 = 0.f, acc3 = 0.f;

    auto flush = [&](int n) {
        float r0 = acc0 + __shfl_xor(acc0, 16, 64);
        float r1 = acc1 + __shfl_xor(acc1, 16, 64);
        float r2 = acc2 + __shfl_xor(acc2, 16, 64);
        float r3 = acc3 + __shfl_xor(acc3, 16, 64);
        r0 += __shfl_xor(r0, 32, 64);
        r1 += __shfl_xor(r1, 32, 64);
        r2 += __shfl_xor(r2, 32, 64);
        r3 += __shfl_xor(r3, 32, 64);
        float v = (q == 0) ? r0 : (q == 1) ? r1 : (q == 2) ? r2 : r3;
        aggr[(size_t)n * 64 + lane] = v;   // plain store: wave owns this node
    };

    // ---- 2-deep pipeline prologue (idx 2 ahead, eab/xb 1 ahead) ----
    int tnA, tnB;
    ushort4v s4A, s4B;
    loadIdx(t0, tnA, s4A);
    loadIdx(clampT(t0 + 1), tnB, s4B);
    bf16x8 efA = loadE(t0);
    short4v xvA0 = *reinterpret_cast<const short4v*>(xb + (size_t)s4A.x * 64 + 4 * c);
    short4v xvA1 = *reinterpret_cast<const short4v*>(xb + (size_t)s4A.y * 64 + 4 * c);
    short4v xvA2 = *reinterpret_cast<const short4v*>(xb + (size_t)s4A.z * 64 + 4 * c);
    short4v xvA3 = *reinterpret_cast<const short4v*>(xb + (size_t)s4A.w * 64 + 4 * c);

    for (int tile = t0; tile < t1; ++tile) {
        // issue next-tile data
        bf16x8 efB = loadE(clampT(tile + 1));
        short4v yv0 = *reinterpret_cast<const short4v*>(xb + (size_t)s4B.x * 64 + 4 * c);
        short4v yv1 = *reinterpret_cast<const short4v*>(xb + (size_t)s4B.y * 64 + 4 * c);
        short4v yv2 = *reinterpret_cast<const short4v*>(xb + (size_t)s4B.z * 64 + 4 * c);
        short4v yv3 = *reinterpret_cast<const short4v*>(xb + (size_t)s4B.w * 64 + 4 * c);
        int tnC; ushort4v s4C;
        loadIdx(clampT(tile + 2), tnC, s4C);

        // flush when owning node changes (wave-uniform branch)
        if (tnA != prev_n) {
            if (prev_n >= 0) flush(prev_n);
            prev_n = tnA;
            acc0 = acc1 = acc2 = acc3 = 0.f;
        }

        f32x4 d[4];
        #pragma unroll
        for (int t = 0; t < 4; ++t)
            d[t] = __builtin_amdgcn_mfma_f32_16x16x32_bf16(efA, bfrag[t], cb[t], 0, 0, 0);

        // accumulate relu(d + x[src]); pads (-1e30 poison) contribute 0
        const short4v xv[4] = {xvA0, xvA1, xvA2, xvA3};
        #pragma unroll
        for (int r = 0; r < 4; ++r) {
            acc0 += fmaxf(d[0][r] + bf2f(xv[r][0]), 0.f);
            acc1 += fmaxf(d[1][r] + bf2f(xv[r][1]), 0.f);
            acc2 += fmaxf(d[2][r] + bf2f(xv[r][2]), 0.f);
            acc3 += fmaxf(d[3][r] + bf2f(xv[r][3]), 0.f);
        }

        // shift pipeline
        tnA = tnB; s4A = s4B;
        tnB = tnC; s4B = s4C;
        efA = efB;
        xvA0 = yv0; xvA1 = yv1; xvA2 = yv2; xvA3 = yv3;
    }
    if (prev_n >= 0) flush(prev_n);
}

// ---------------------------------------------------------------------------
// Node kernel (MFMA): wave per 16-node tile.
// h = relu((x + aggr) @ Wab + bab); writes f32 h and permuted bf16 hb.
// ---------------------------------------------------------------------------
__global__ void __launch_bounds__(256) node_kernel(
    const float* __restrict__ x,
    const float* __restrict__ aggr,
    const float* __restrict__ Wab,    // [64,64] f32
    const float* __restrict__ bab,    // [64]
    float* __restrict__ out,          // [N,64]
    short* __restrict__ hb)           // [N(+1),64] bf16 permuted
{
    const int lane = threadIdx.x & 63;
    const int q = lane >> 4;
    const int c = lane & 15;
    const int wave = (blockIdx.x * blockDim.x + threadIdx.x) >> 6;
    const int nwav = (gridDim.x * blockDim.x) >> 6;

    bf16x8 bfrag[2][4];
    #pragma unroll
    for (int kk = 0; kk < 2; ++kk) {
        #pragma unroll
        for (int t = 0; t < 4; ++t) {
            #pragma unroll
            for (int e = 0; e < 8; ++e) {
                int k = 32 * kk + 4 * q + (e & 3) + 16 * (e >> 2);
                bfrag[kk][t][e] = f2bf(Wab[k * 64 + 16 * t + c]);
            }
        }
    }
    f32x4 cb[4];
    #pragma unroll
    for (int t = 0; t < 4; ++t) {
        float bv = bab[16 * t + c];
        cb[t][0] = bv; cb[t][1] = bv; cb[t][2] = bv; cb[t][3] = bv;
    }

    const int ntile = N_NODES / 16;   // 3125 exact
    for (int nt = wave; nt < ntile; nt += nwav) {
        const int n0 = nt * 16;
        const float* xr = x    + (size_t)(n0 + c) * 64;
        const float* ar = aggr + (size_t)(n0 + c) * 64;
        float4 v[4];
        #pragma unroll
        for (int j = 0; j < 4; ++j) {
            int off = (j >> 1) * 32 + (j & 1) * 16 + 4 * q;
            float4 a = *reinterpret_cast<const float4*>(xr + off);
            float4 b = *reinterpret_cast<const float4*>(ar + off);
            v[j].x = a.x + b.x; v[j].y = a.y + b.y;
            v[j].z = a.z + b.z; v[j].w = a.w + b.w;
        }
        f32x4 d[4];
        #pragma unroll
        for (int kk = 0; kk < 2; ++kk) {
            int4 ai;
            ai.x = cvt_pk_bf16(v[2 * kk].x, v[2 * kk].y);
            ai.y = cvt_pk_bf16(v[2 * kk].z, v[2 * kk].w);
            ai.z = cvt_pk_bf16(v[2 * kk + 1].x, v[2 * kk + 1].y);
            ai.w = cvt_pk_bf16(v[2 * kk + 1].z, v[2 * kk + 1].w);
            bf16x8 afrag = __builtin_bit_cast(bf16x8, ai);
            #pragma unroll
            for (int t = 0; t < 4; ++t)
                d[t] = __builtin_amdgcn_mfma_f32_16x16x32_bf16(
                    afrag, bfrag[kk][t], kk == 0 ? cb[t] : d[t], 0, 0, 0);
        }
        #pragma unroll
        for (int r = 0; r < 4; ++r) {
            float h0 = fmaxf(d[0][r], 0.f);
            float h1v = fmaxf(d[1][r], 0.f);
            float h2v = fmaxf(d[2][r], 0.f);
            float h3 = fmaxf(d[3][r], 0.f);
            float* orow = out + (size_t)(n0 + 4 * q + r) * 64;
            orow[c]      = h0;
            orow[16 + c] = h1v;
            orow[32 + c] = h2v;
            orow[48 + c] = h3;
            int2 pk;
            pk.x = cvt_pk_bf16(h0, h1v);
            pk.y = cvt_pk_bf16(h2v, h3);
            *reinterpret_cast<int2*>(hb + (size_t)(n0 + 4 * q + r) * 64 + 4 * c) = pk;
        }
    }
}

__global__ void prep_kernel(
    const float* __restrict__ Wa1, const float* __restrict__ ba1,
    const float* __restrict__ Wb1, const float* __restrict__ bb1,
    const float* __restrict__ Wa2, const float* __restrict__ ba2,
    const float* __restrict__ Wb2, const float* __restrict__ bb2,
    float* __restrict__ Wab1, float* __restrict__ bab1,
    float* __restrict__ Wab2, float* __restrict__ bab2)
{
    const int t = threadIdx.x;
    for (int idx = t; idx < 64 * 64; idx += 256) {
        int i = idx >> 6, j = idx & 63;
        float s1 = 0.f, s2 = 0.f;
        for (int m = 0; m < 64; ++m) {
            s1 += Wa1[i * 64 + m] * Wb1[m * 64 + j];
            s2 += Wa2[i * 64 + m] * Wb2[m * 64 + j];
        }
        Wab1[idx] = s1; Wab2[idx] = s2;
    }
    for (int j = t; j < 64; j += 256) {
        float s1 = bb1[j], s2 = bb2[j];
        for (int m = 0; m < 64; ++m) {
            s1 += ba1[m] * Wb1[m * 64 + j];
            s2 += ba2[m] * Wb2[m * 64 + j];
        }
        bab1[j] = s1; bab2[j] = s2;
    }
}

__global__ void __launch_bounds__(256) pool_kernel(
    const float* __restrict__ h,
    const int*   __restrict__ batch,
    float* __restrict__ psum,
    float* __restrict__ pcnt)
{
    const int lane = threadIdx.x & 63;
    const int wave = (blockIdx.x * blockDim.x + threadIdx.x) >> 6;
    const int n0 = wave * 64;
    if (n0 >= N_NODES) return;
    const int nend = min(n0 + 64, N_NODES);

    int cur = batch[n0];
    float acc = 0.f;
    int cnt = 0;
    for (int n = n0; n < nend; ++n) {
        int b = batch[n];
        if (b != cur) {
            atomicAdd(&psum[(size_t)cur * 64 + lane], acc);
            if (lane == 0) atomicAdd(&pcnt[cur], (float)cnt);
            cur = b; acc = 0.f; cnt = 0;
        }
        acc += h[(size_t)n * 64 + lane];
        cnt++;
    }
    atomicAdd(&psum[(size_t)cur * 64 + lane], acc);
    if (lane == 0) atomicAdd(&pcnt[cur], (float)cnt);
}

__global__ void final_kernel(
    const float* __restrict__ psum, const float* __restrict__ pcnt,
    const float* __restrict__ Wf, const float* __restrict__ bfv,
    float* __restrict__ out)
{
    __shared__ float pooled[NUM_GRAPHS * 64];
    __shared__ float logits[NUM_GRAPHS * NUM_CLASSES];
    const int t = threadIdx.x;
    for (int idx = t; idx < NUM_GRAPHS * 64; idx += 256) {
        int g = idx >> 6;
        float cc = pcnt[g];
        cc = cc < 1.f ? 1.f : cc;
        pooled[idx] = psum[idx] / cc;
    }
    __syncthreads();
    for (int idx = t; idx < NUM_GRAPHS * NUM_CLASSES; idx += 256) {
        int g = idx / NUM_CLASSES, cc = idx % NUM_CLASSES;
        float acc = bfv[cc];
        for (int k = 0; k < 64; ++k)
            acc += pooled[g * 64 + k] * Wf[k * NUM_CLASSES + cc];
        logits[idx] = acc;
    }
    __syncthreads();
    if (t < NUM_GRAPHS) {
        float mx = -1e30f;
        for (int cc = 0; cc < NUM_CLASSES; ++cc)
            mx = fmaxf(mx, logits[t * NUM_CLASSES + cc]);
        float s = 0.f;
        float ex[NUM_CLASSES];
        for (int cc = 0; cc < NUM_CLASSES; ++cc) {
            ex[cc] = expf(logits[t * NUM_CLASSES + cc] - mx);
            s += ex[cc];
        }
        for (int cc = 0; cc < NUM_CLASSES; ++cc)
            out[t * NUM_CLASSES + cc] = ex[cc] / s;
    }
}

extern "C" void kernel_launch(void* const* d_in, const int* in_sizes, int n_in,
                              void* d_out, int out_size, void* d_ws, size_t ws_size,
                              hipStream_t stream) {
    const float* x   = (const float*)d_in[0];
    const float* ea  = (const float*)d_in[1];
    const float* We1 = (const float*)d_in[2];
    const float* be1 = (const float*)d_in[3];
    const float* W1a = (const float*)d_in[4];
    const float* b1a = (const float*)d_in[5];
    const float* W1b = (const float*)d_in[6];
    const float* b1b = (const float*)d_in[7];
    const float* We2 = (const float*)d_in[8];
    const float* be2 = (const float*)d_in[9];
    const float* W2a = (const float*)d_in[10];
    const float* b2a = (const float*)d_in[11];
    const float* W2b = (const float*)d_in[12];
    const float* b2b = (const float*)d_in[13];
    const float* Wf  = (const float*)d_in[14];
    const float* bfv = (const float*)d_in[15];
    const int* ei    = (const int*)d_in[16];
    const int* batch = (const int*)d_in[17];
    const int* src = ei;
    const int* dst = ei + N_EDGES;

    // workspace layout (offsets in 4-byte units from base; total ~58.6M ints
    // = 234 MB)
    int* wsb = (int*)d_ws;
    float* aggr = (float*)wsb;                         // [0, 3.2M)
    float* h1   = (float*)(wsb + 3200000);             // [3.2M, 6.4M)
    float* h2   = (float*)(wsb + 6400000);             // [6.4M, 9.6M)
    short* eab  = (short*)(wsb + 9600000);             // 35,200,000 ints
    int2*  bbuf = (int2*)(wsb + 44800000);             // 4,816,896 ints
    short* xb   = (short*)(wsb + 49616896);            // 1,600,032 ints
    short* hb1  = (short*)(wsb + 51216928);            // 1,600,032 ints
    short* hb2  = (short*)(wsb + 52816960);            // 1,600,032 ints
    unsigned short* ssrc = (unsigned short*)(wsb + 54416992); // 1,100,000 ints
    int* tnode  = wsb + 55516992;                      // 137,500 ints
    float* Wab1 = (float*)(wsb + 55654492);            // 4096
    float* bab1 = Wab1 + 4096;                         // 64
    float* Wab2 = bab1 + 64;                           // 4096
    float* bab2 = Wab2 + 4096;                         // 64
    float* psum = bab2 + 64;                           // 8192
    float* pcnt = psum + 8192;                         // 128
    int* cnt    = (int*)(pcnt + 128);                  // NBIN_PAD
    int* pstart = cnt + NBIN_PAD;                      // NBIN_PAD
    int* partial= pstart + NBIN_PAD;                   // 256
    int* bcur   = partial + 256;                       // 256
    unsigned short* rank16 = (unsigned short*)(bcur + 256); // NBUCK*BCAP ushorts
    int* pos    = (int*)(rank16 + (size_t)NBUCK * BCAP);    // N_EDGES ints

    float* out = (float*)d_out;

    // ---- padded-CSR build: counting sort with deterministic ranks; the
    //      permutation is applied as a streaming-read + full-line random-
    //      WRITE scatter (eascatter v2, 4 lanes/edge) ----
    hipMemsetAsync(bcur, 0, 256 * sizeof(int), stream);
    binA_kernel<<<(N_EDGES + ACH - 1) / ACH, 256, 0, stream>>>(src, dst, bcur, bbuf);
    binB1_kernel<<<NBUCK, 1024, 0, stream>>>(bcur, bbuf, cnt, rank16);
    scan_part<<<NSCAN_BLK, 256, 0, stream>>>(cnt, pstart, partial);
    scan_mid<<<1, 256, 0, stream>>>(partial);
    scan_add<<<NSCAN_BLK, 256, 0, stream>>>(pstart, partial);
    pos_kernel<<<NBUCK, 1024, 0, stream>>>(bcur, bbuf, rank16, pstart, pos, ssrc);
    eascatter_kernel<<<(N_EDGES + 63) / 64, 256, 0, stream>>>(ea, pos, eab);
    pad_kernel<<<NSCAN_BLK, 256, 0, stream>>>(pstart, cnt, ssrc, eab, tnode, aggr);
    xprep_kernel<<<((N_NODES + 1) * 64 + 255) / 256, 256, 0, stream>>>(x, xb, hb1);

    hipMemsetAsync(psum, 0, (8192 + 128) * sizeof(float), stream);
    prep_kernel<<<1, 256, 0, stream>>>(W1a, b1a, W1b, b1b, W2a, b2a, W2b, b2b,
                                       Wab1, bab1, Wab2, bab2);

    // no aggr memsets: node-aligned wave ownership -> plain stores cover all
    // deg>0 nodes; pad_kernel zeroed deg-0 rows.
    edge_kernel<<<2048, 256, 0, stream>>>(xb, eab, ssrc, We1, be1, tnode, pstart, aggr);
    node_kernel<<<512, 256, 0, stream>>>(x, aggr, Wab1, bab1, h1, hb1);

    edge_kernel<<<2048, 256, 0, stream>>>(hb1, eab, ssrc, We2, be2, tnode, pstart, aggr);
    node_kernel<<<512, 256, 0, stream>>>(h1, aggr, Wab2, bab2, h2, hb2);

    pool_kernel<<<196, 256, 0, stream>>>(h2, batch, psum, pcnt);
    final_kernel<<<1, 256, 0, stream>>>(psum, pcnt, Wf, bfv, out);
}